// Round 7
// baseline (42.526 us; speedup 1.0000x reference)
//
#include <hip/hip_runtime.h>
#include <hip/hip_bf16.h>
#include <math.h>

#define N_NODES 512
#define S_STEPS 64
#define M_EV    32768
#define DELTA_F 1.5625f
#define EPS_F   1e-12f
#define TILE    16
#define NT      (N_NODES / TILE)        // 32
#define NOFF    (NT * (NT - 1) / 2)     // 496 strict-upper tiles
#define NBLK    (NOFF + NT / 2)         // 512 blocks total
#define SCHUNK  16
#define FIX_SCALE 1048576.0             // 2^20

// ws layout:
//   byte 0:    float4 sC[64]  (c0, 2*c1, c2, T_eff)        1 KB
//   byte 2048: u64 accD, accI; u32 ticket                  20 B

// branchless erf, Abramowitz-Stegun 7.1.26 (|abs err| ~ 3e-7)
__device__ __forceinline__ float erf_fast(float x) {
    float ax = fabsf(x);
    float t  = __builtin_amdgcn_rcpf(fmaf(0.3275911f, ax, 1.0f));
    float y  = t * fmaf(t, fmaf(t, fmaf(t, fmaf(t, 1.061405429f, -1.453152027f),
                                          1.421413741f), -0.284496736f), 0.254829592f);
    float e  = __expf(-ax * ax);
    float r  = fmaf(-y, e, 1.0f);
    return __builtin_copysignf(r, x);
}

// one block per bucket; 1024 threads scan all M events with independent loads
__global__ __launch_bounds__(1024) void bucket_scan(const float* __restrict__ data,
                                                    float4* __restrict__ ws_c4,
                                                    unsigned long long* __restrict__ acc) {
    int b   = blockIdx.x;
    int tid = threadIdx.x;
    __shared__ int   scnt[16], slo[16], shi[16];
    __shared__ float ssdd[16], ssdd2[16];

    if (b == 0 && tid == 512) {          // zero fused-finalize state (stream-ordered)
        acc[0] = 0ull; acc[1] = 0ull;
        ((unsigned int*)acc)[4] = 0u;    // ticket at byte offset 16
    }

    int   cnt = 0;
    float sdd = 0.f, sdd2 = 0.f;
    int   lo = 0x7fffffff, hi = 0x7fffffff;
    #pragma unroll 4
    for (int k = 0; k < M_EV / 1024; ++k) {
        int m = tid + (k << 10);
        float t = data[3 * m + 2];
        float stepf = floorf(t / DELTA_F);                 // same expr as verified rounds
        float keyf  = fminf(fmaxf(stepf, 0.f), 63.f);
        int   key   = (int)keyf;
        if (key == b) {
            float dd = t - stepf * DELTA_F;
            cnt++; sdd += dd; sdd2 += dd * dd;
            lo = min(lo, m);
        }
        if (key > b) hi = min(hi, m);                      // == lower_bound(b+1)
    }
    for (int off = 32; off; off >>= 1) {
        cnt  += __shfl_down(cnt,  off);
        sdd  += __shfl_down(sdd,  off);
        sdd2 += __shfl_down(sdd2, off);
        lo    = min(lo, __shfl_down(lo, off));
        hi    = min(hi, __shfl_down(hi, off));
    }
    int wave = tid >> 6, lane = tid & 63;
    if (lane == 0) { scnt[wave] = cnt; ssdd[wave] = sdd; ssdd2[wave] = sdd2;
                     slo[wave] = lo; shi[wave] = hi; }
    __syncthreads();
    if (tid == 0) {
        int c = 0, l2 = 0x7fffffff, h2 = 0x7fffffff;
        float s1 = 0.f, s2 = 0.f;
        #pragma unroll
        for (int k = 0; k < 16; ++k) {
            c += scnt[k]; s1 += ssdd[k]; s2 += ssdd2[k];
            l2 = min(l2, slo[k]); h2 = min(h2, shi[k]);
        }
        float ts = data[3 * min(l2, M_EV - 1) + 2];
        float tf = data[3 * min(h2, M_EV - 1) + 2];
        float Teff = (c > 0) ? (tf - ts) : 0.f;            // T=0 -> erf diff == 0
        ws_c4[b] = make_float4((float)c, 2.f * s1, s2, Teff);
    }
}

__global__ __launch_bounds__(1024, 8) void pair_kernel(
        const float* __restrict__ z0, const float* __restrict__ v0,
        const float* __restrict__ beta, const float4* __restrict__ ws_c4,
        unsigned long long* __restrict__ acc, float* __restrict__ out) {
    __shared__ float4 Pi[S_STEPS][17];
    __shared__ float4 Pj[S_STEPS][17];
    __shared__ float4 sC[64];
    __shared__ double wD[16], wI[16];

    int l = blockIdx.x;
    bool isDiag = (l >= NOFF);
    int it, jt;
    if (!isDiag) {                 // strict upper-tri tile enumeration
        int it_ = 0, rem = l;
        while (rem >= NT - 1 - it_) { rem -= NT - 1 - it_; ++it_; }
        it = it_; jt = it_ + 1 + rem;
    } else {                       // two diagonal tiles per block
        int k = l - NOFF;
        it = 2 * k; jt = 2 * k + 1;
    }

    int tid  = threadIdx.x;
    int wave = tid >> 6, lane = tid & 63;   // 16 waves of 64

    if (tid < 64) sC[tid] = ws_c4[tid];

    // staging: 16 waves x 2 slab entries; lane == step s; wave-64 prefix scan gives Z
    for (int e = wave * 2; e < wave * 2 + 2; ++e) {
        int loc = e & 15;
        int n = (e < 16 ? it : jt) * TILE + loc;
        float vx = v0[n * 128 + lane];
        float vy = v0[n * 128 + 64 + lane];
        float ix = vx, iy = vy;
        #pragma unroll
        for (int off = 1; off < 64; off <<= 1) {
            float ux = __shfl_up(ix, off);
            float uy = __shfl_up(iy, off);
            if (lane >= off) { ix += ux; iy += uy; }
        }
        float zx = fmaf(DELTA_F, ix - vx, z0[2 * n]);      // exclusive prefix
        float zy = fmaf(DELTA_F, iy - vy, z0[2 * n + 1]);
        float4 val = make_float4(zx, zy, vx, vy);
        if (e < 16) Pi[lane][loc] = val; else Pj[lane][loc] = val;
    }
    __syncthreads();

    // compute: 4 chunks x 256 threads; each active thread = one (i,j) pair, 16 steps
    int chunk = tid >> 8;
    int r  = tid & 255;
    int li = r >> 4, lj = r & 15;

    const float4* rowA;
    const float4* rowB;
    bool act;
    if (!isDiag) {
        rowA = &Pi[0][li]; rowB = &Pj[0][lj]; act = true;
    } else if (li < lj) {
        rowA = &Pi[0][li]; rowB = &Pi[0][lj]; act = true;
    } else {
        int bb = min(li + 1, 15);
        rowA = &Pj[0][lj]; rowB = &Pj[0][bb]; act = (li < 15);
    }

    float accD = 0.f, accI = 0.f;
    float b = beta[0];

    if (act) {
        int s0 = chunk * SCHUNK;
        const float4* pA = rowA + s0 * 17;
        const float4* pB = rowB + s0 * 17;
        #pragma unroll 4
        for (int ss = 0; ss < SCHUNK; ++ss) {
            float4 a = pA[ss * 17];
            float4 c = pB[ss * 17];
            float4 k = sC[s0 + ss];
            float dx  = a.x - c.x,  dy  = a.y - c.y;
            float dvx = a.z - c.z,  dvy = a.w - c.w;
            float q  = dx * dx + dy * dy;
            float p  = fmaf(dx, dvx, dy * dvy);
            float vv = fmaf(dvx, dvx, dvy * dvy);
            accD += fmaf(k.x, q, fmaf(k.y, p, k.z * vv));
            float rr    = vv + EPS_F;
            float inv_r = __builtin_amdgcn_rsqf(rr);
            float rt    = rr * inv_r;
            float por   = p * inv_r;
            float ex    = __expf(fmaf(por, por, b - q));   // por^2 <= q -> ex <= e^b
            float integ = ex * (0.8862269254527580f * inv_r)
                          * (erf_fast(fmaf(rt, k.w, por)) - erf_fast(por));
            accI += integ;                                  // T_eff==0 -> integ==0
        }
    }

    // deterministic reduce: wave tree -> 16 wave partials -> tid 0 -> i64 atomics
    for (int off = 32; off; off >>= 1) {
        accD += __shfl_down(accD, off);
        accI += __shfl_down(accI, off);
    }
    if (lane == 0) { wD[wave] = (double)accD; wI[wave] = (double)accI; }
    __syncthreads();
    if (tid == 0) {
        double D = 0.0, I = 0.0;
        #pragma unroll
        for (int k = 0; k < 16; ++k) { D += wD[k]; I += wI[k]; }
        unsigned long long o0 = atomicAdd(&acc[0],
            (unsigned long long)(long long)llrint(D * FIX_SCALE));
        unsigned long long o1 = atomicAdd(&acc[1],
            (unsigned long long)(long long)llrint(I * FIX_SCALE));
        // consume returns: forces s_waitcnt on the acc RMWs (completion at LLC)
        // before the ticket RMW below can issue -- no cache-flushing threadfence.
        asm volatile("" : : "v"((unsigned int)o0), "v"((unsigned int)o1) : "memory");
        unsigned int t = atomicAdd(&((unsigned int*)acc)[4], 1u);
        if (t == (unsigned int)(NBLK - 1)) {
            unsigned long long Du = atomicAdd(&acc[0], 0ull);  // returning: waits
            unsigned long long Iu = atomicAdd(&acc[1], 0ull);
            double Dd = (double)(long long)Du / FIX_SCALE;
            double Id = (double)(long long)Iu / FIX_SCALE;
            double npairs = (double)N_NODES * (double)(N_NODES - 1) * 0.5;
            out[0] = (float)((double)b * (double)M_EV * npairs - Dd - Id);
        }
    }
}

extern "C" void kernel_launch(void* const* d_in, const int* in_sizes, int n_in,
                              void* d_out, int out_size, void* d_ws, size_t ws_size,
                              hipStream_t stream) {
    const float* data = (const float*)d_in[0];
    const float* z0   = (const float*)d_in[3];
    const float* v0   = (const float*)d_in[4];
    const float* beta = (const float*)d_in[5];

    float4* ws_c4 = (float4*)d_ws;
    unsigned long long* acc = (unsigned long long*)((char*)d_ws + 2048);
    float* out = (float*)d_out;

    bucket_scan<<<64, 1024, 0, stream>>>(data, ws_c4, acc);
    pair_kernel<<<NBLK, 1024, 0, stream>>>(z0, v0, beta, ws_c4, acc, out);
}

// Round 8
// 28.008 us; speedup vs baseline: 1.5184x; 1.5184x over previous
//
#include <hip/hip_runtime.h>
#include <hip/hip_bf16.h>
#include <math.h>

#define N_NODES 512
#define S_STEPS 64
#define M_EV    32768
#define DELTA_F 1.5625f
#define EPS_F   1e-12f
#define TILE    16
#define NT      (N_NODES / TILE)        // 32
#define NOFF    (NT * (NT - 1) / 2)     // 496 strict-upper tiles
#define NBLK    (NOFF + NT / 2)         // 512 blocks total

// ws layout:
//   byte 0:    float4 sC[64]  (c0, 2*c1, c2, T_eff)        1 KB
//   byte 2048: double partials[NBLK*2]                     8 KB

__device__ __forceinline__ int bucket_key(float t) {
    float stepf = floorf(t / DELTA_F);
    float cl = fminf(fmaxf(stepf, 0.f), 63.f);
    return (int)cl;
}

__device__ __forceinline__ int lower_bound_key(const float* __restrict__ data, int target) {
    int lo = 0, len = M_EV;
    while (len > 0) {
        int half = len >> 1;
        int mid = lo + half;
        if (bucket_key(data[3 * mid + 2]) < target) { lo = mid + 1; len -= half + 1; }
        else { len = half; }
    }
    return lo;
}

// branchless erf, Abramowitz-Stegun 7.1.26 (|abs err| ~ 3e-7)
__device__ __forceinline__ float erf_fast(float x) {
    float ax = fabsf(x);
    float t  = __builtin_amdgcn_rcpf(fmaf(0.3275911f, ax, 1.0f));
    float y  = t * fmaf(t, fmaf(t, fmaf(t, fmaf(t, 1.061405429f, -1.453152027f),
                                          1.421413741f), -0.284496736f), 0.254829592f);
    float e  = __expf(-ax * ax);
    float r  = fmaf(-y, e, 1.0f);
    return __builtin_copysignf(r, x);
}

// one pair-step evaluation; accumulates into accD/accI
__device__ __forceinline__ void pair_step(const float4 a, const float4 c, const float4 k,
                                          float b, float& accD, float& accI) {
    float dx  = a.x - c.x,  dy  = a.y - c.y;
    float dvx = a.z - c.z,  dvy = a.w - c.w;
    float q  = dx * dx + dy * dy;
    float p  = fmaf(dx, dvx, dy * dvy);
    float vv = fmaf(dvx, dvx, dvy * dvy);
    accD += fmaf(k.x, q, fmaf(k.y, p, k.z * vv));
    float rr    = vv + EPS_F;
    float inv_r = __builtin_amdgcn_rsqf(rr);
    float rt    = rr * inv_r;
    float por   = p * inv_r;
    float ex    = __expf(fmaf(por, por, b - q));   // por^2 <= q -> ex <= e^b
    float integ = ex * (0.8862269254527580f * inv_r)
                  * (erf_fast(fmaf(rt, k.w, por)) - erf_fast(por));
    accI += integ;                                  // T_eff==0 -> integ==0
}

__global__ __launch_bounds__(256) void bucket_stats(const float* __restrict__ data,
                                                    float4* __restrict__ ws_c4) {
    int s   = blockIdx.x;
    int tid = threadIdx.x;
    __shared__ int sLo, sHi;
    __shared__ int   wcnt[4];
    __shared__ float wsdd[4], wsdd2[4];

    if (tid == 0)  sLo = lower_bound_key(data, s);
    if (tid == 64) sHi = lower_bound_key(data, s + 1);
    __syncthreads();
    int lo = sLo, hi = sHi;

    int   cnt = 0;
    float sdd = 0.f, sdd2 = 0.f;
    for (int m = lo + tid; m < hi; m += 256) {
        float t = data[3 * m + 2];
        float stepf = floorf(t / DELTA_F);
        float dd = t - stepf * DELTA_F;
        cnt++; sdd += dd; sdd2 += dd * dd;
    }
    for (int off = 32; off; off >>= 1) {
        cnt  += __shfl_down(cnt,  off);
        sdd  += __shfl_down(sdd,  off);
        sdd2 += __shfl_down(sdd2, off);
    }
    int wave = tid >> 6;
    if ((tid & 63) == 0) { wcnt[wave] = cnt; wsdd[wave] = sdd; wsdd2[wave] = sdd2; }
    __syncthreads();
    if (tid == 0) {
        int   c  = wcnt[0] + wcnt[1] + wcnt[2] + wcnt[3];
        float s1 = wsdd[0] + wsdd[1] + wsdd[2] + wsdd[3];
        float s2 = wsdd2[0] + wsdd2[1] + wsdd2[2] + wsdd2[3];
        float ts = data[3 * min(lo, M_EV - 1) + 2];
        float tf = data[3 * min(hi, M_EV - 1) + 2];
        float Teff = (c > 0) ? (tf - ts) : 0.f;   // T=0 => erf diff == 0 exactly
        ws_c4[s] = make_float4((float)c, 2.f * s1, s2, Teff);
    }
}

__global__ __launch_bounds__(1024, 8) void pair_kernel(
        const float* __restrict__ z0, const float* __restrict__ v0,
        const float* __restrict__ beta, const float4* __restrict__ ws_c4,
        double* __restrict__ partials) {
    __shared__ float4 Pi[S_STEPS][17];
    __shared__ float4 Pj[S_STEPS][17];
    __shared__ float4 sC[64];
    __shared__ double wD[16], wI[16];

    int l = blockIdx.x;
    bool isDiag = (l >= NOFF);
    int it, jt;
    if (!isDiag) {                 // strict upper-tri tile enumeration
        int it_ = 0, rem = l;
        while (rem >= NT - 1 - it_) { rem -= NT - 1 - it_; ++it_; }
        it = it_; jt = it_ + 1 + rem;
    } else {                       // two diagonal tiles per block
        int k = l - NOFF;
        it = 2 * k; jt = 2 * k + 1;
    }

    int tid  = threadIdx.x;
    int wave = tid >> 6, lane = tid & 63;   // 16 waves of 64

    if (tid < 64) sC[tid] = ws_c4[tid];

    // staging: 16 waves x 2 slab entries; lane == step s; wave-64 prefix scan gives Z
    for (int e = wave * 2; e < wave * 2 + 2; ++e) {
        int loc = e & 15;
        int n = (e < 16 ? it : jt) * TILE + loc;
        float vx = v0[n * 128 + lane];
        float vy = v0[n * 128 + 64 + lane];
        float ix = vx, iy = vy;
        #pragma unroll
        for (int off = 1; off < 64; off <<= 1) {
            float ux = __shfl_up(ix, off);
            float uy = __shfl_up(iy, off);
            if (lane >= off) { ix += ux; iy += uy; }
        }
        float zx = fmaf(DELTA_F, ix - vx, z0[2 * n]);      // exclusive prefix
        float zy = fmaf(DELTA_F, iy - vy, z0[2 * n + 1]);
        float4 val = make_float4(zx, zy, vx, vy);
        if (e < 16) Pi[lane][loc] = val; else Pj[lane][loc] = val;
    }
    __syncthreads();

    // compute: 8 chunks x 128 threads; each thread = 2 pairs sharing lj, 8 steps
    int chunk = tid >> 7;          // s-range [chunk*8, chunk*8+8)
    int r   = tid & 127;
    int lj  = r & 15;
    int li0 = r >> 4;              // 0..7
    int li1 = li0 + 8;             // 8..15

    float accD = 0.f, accI = 0.f;
    float b = beta[0];
    int s0 = chunk * 8;
    const float4* pK = &sC[s0];

    if (!isDiag) {
        // i < j always; c and k shared between the two pairs
        const float4* pA0 = &Pi[s0][li0];
        const float4* pA1 = &Pi[s0][li1];
        const float4* pC  = &Pj[s0][lj];
        #pragma unroll 2
        for (int ss = 0; ss < 8; ++ss) {
            float4 c  = pC[ss * 17];
            float4 k  = pK[ss];
            float4 a0 = pA0[ss * 17];
            float4 a1 = pA1[ss * 17];
            pair_step(a0, c, k, b, accD, accI);
            pair_step(a1, c, k, b, accD, accI);
        }
    } else {
        // per-pair decode (round-6 verified triangle-in-square bijection)
        const float4 *rA0, *rB0, *rA1, *rB1;
        bool act0, act1;
        if (li0 < lj) { rA0 = &Pi[s0][li0]; rB0 = &Pi[s0][lj]; act0 = true; }
        else { int bb = min(li0 + 1, 15); rA0 = &Pj[s0][lj]; rB0 = &Pj[s0][bb]; act0 = (li0 < 15); }
        if (li1 < lj) { rA1 = &Pi[s0][li1]; rB1 = &Pi[s0][lj]; act1 = true; }
        else { int bb = min(li1 + 1, 15); rA1 = &Pj[s0][lj]; rB1 = &Pj[s0][bb]; act1 = (li1 < 15); }
        #pragma unroll 2
        for (int ss = 0; ss < 8; ++ss) {
            float4 k = pK[ss];
            if (act0) pair_step(rA0[ss * 17], rB0[ss * 17], k, b, accD, accI);
            if (act1) pair_step(rA1[ss * 17], rB1[ss * 17], k, b, accD, accI);
        }
    }

    // deterministic reduce: wave tree -> 16 wave partials -> tid 0 sums -> plain store
    for (int off = 32; off; off >>= 1) {
        accD += __shfl_down(accD, off);
        accI += __shfl_down(accI, off);
    }
    if (lane == 0) { wD[wave] = (double)accD; wI[wave] = (double)accI; }
    __syncthreads();
    if (tid == 0) {
        double D = 0.0, I = 0.0;
        #pragma unroll
        for (int k = 0; k < 16; ++k) { D += wD[k]; I += wI[k]; }
        partials[2 * l]     = D;
        partials[2 * l + 1] = I;
    }
}

__global__ void final_reduce(const float* __restrict__ beta,
                             const double* __restrict__ partials,
                             float* __restrict__ out) {
    __shared__ double sD[256], sI[256];
    int tid = threadIdx.x;
    double dD = 0.0, dI = 0.0;
    for (int l = tid; l < NBLK; l += 256) {
        dD += partials[2 * l];
        dI += partials[2 * l + 1];
    }
    sD[tid] = dD; sI[tid] = dI;
    __syncthreads();
    for (int off = 128; off; off >>= 1) {
        if (tid < off) { sD[tid] += sD[tid + off]; sI[tid] += sI[tid + off]; }
        __syncthreads();
    }
    if (tid == 0) {
        double npairs = (double)N_NODES * (double)(N_NODES - 1) * 0.5;
        double ev = (double)beta[0] * (double)M_EV * npairs - sD[0];
        out[0] = (float)(ev - sI[0]);
    }
}

extern "C" void kernel_launch(void* const* d_in, const int* in_sizes, int n_in,
                              void* d_out, int out_size, void* d_ws, size_t ws_size,
                              hipStream_t stream) {
    const float* data = (const float*)d_in[0];
    const float* z0   = (const float*)d_in[3];
    const float* v0   = (const float*)d_in[4];
    const float* beta = (const float*)d_in[5];

    float4* ws_c4    = (float4*)d_ws;
    double* partials = (double*)((char*)d_ws + 2048);
    float*  out      = (float*)d_out;

    bucket_stats<<<64, 256, 0, stream>>>(data, ws_c4);
    pair_kernel<<<NBLK, 1024, 0, stream>>>(z0, v0, beta, ws_c4, partials);
    final_reduce<<<1, 256, 0, stream>>>(beta, partials, out);
}